// Round 1
// baseline (522.454 us; speedup 1.0000x reference)
//
#include <hip/hip_runtime.h>
#include <hip/hip_bf16.h>
#include <cstdint>
#include <cstddef>

// ---------------------------------------------------------------------------
// STGNN forward. Round 6: XCD-range-partitioned bucket build.
//  - build_buckets was write-amplification-bound (49.4 MB HBM writes vs
//    ~6.8 MB payload: random 8B int2 stores, one 64B line writeback each,
//    bounced across 8 non-coherent XCD L2s).
//  - Now: nodes split into 8 ranges, range = blockIdx.x & 7 (== XCD under
//    round-robin dispatch). Each range-group streams the full edge list
//    (L2/L3-resident, cheap) and writes only its 1/8 bucket slice (~3.2 MB,
//    fits one XCD's 4 MiB L2) -> lines fill completely before writeback.
//    Mapping is a locality heuristic only; correctness independent of it.
//  - Everything else unchanged from round 5 (zero-atomic edge phase, fused
//    attention dots in GEMM epilogue, wave-per-node gather).
// ---------------------------------------------------------------------------

#define LRELU_SLOPE 0.2f
#define CAP 64
#define NRANGE 8

typedef __attribute__((ext_vector_type(8))) short short8;
typedef __attribute__((ext_vector_type(4))) float floatx4;

__device__ __forceinline__ float bf2f(ushort u) {
    union { unsigned int u32; float f; } v; v.u32 = ((unsigned int)u) << 16; return v.f;
}
__device__ __forceinline__ ushort f2bf(float x) {
    union { float f; unsigned int u; } v; v.f = x;
    unsigned int r = (v.u + 0x7FFFu + ((v.u >> 16) & 1u)) >> 16;
    return (ushort)r;
}

// ---------------- elementwise fp32 -> bf16 cast (4/thread) ------------------
__global__ __launch_bounds__(256) void cast_bf16(
    const float* __restrict__ x, ushort* __restrict__ y, int n4)
{
    const int idx = blockIdx.x * blockDim.x + threadIdx.x;
    if (idx >= n4) return;
    float4 v = ((const float4*)x)[idx];
    ushort4 o;
    o.x = f2bf(v.x); o.y = f2bf(v.y); o.z = f2bf(v.z); o.w = f2bf(v.w);
    ((ushort4*)y)[idx] = o;
}

// ------------- weight transpose+cast: W[K][256] f32 -> WT[256][K] bf16 ------
__global__ __launch_bounds__(256) void wtrans(
    const float* __restrict__ W, ushort* __restrict__ WT, int K)
{
    const int idx = blockIdx.x * blockDim.x + threadIdx.x;
    if (idx >= K * 256) return;
    const int k = idx >> 8, n = idx & 255;
    WT[n * K + k] = f2bf(W[idx]);
}

// ---------------- bf16 MFMA GEMM: C[M,256] = act(A[M,K] @ B + bias) ---------
// blockIdx.y = head (64 cols). Optional fused per-row attention dot:
// aSo[row,head] = <C_row_head, attS_head>, same for aDo.
__global__ __launch_bounds__(256) void gemm_bf16(
    const ushort* __restrict__ A, const ushort* __restrict__ Bt,
    const float* __restrict__ bias, float* __restrict__ Cf,
    ushort* __restrict__ Cb, int M, int K, int do_relu,
    const float* __restrict__ attS, const float* __restrict__ attD,
    float* __restrict__ aSo, float* __restrict__ aDo)
{
    __shared__ short As[64][40];   // +8 pad
    __shared__ short Bs[64][40];
    const int tid  = threadIdx.x;
    const int row0 = blockIdx.x * 64;
    const int col0 = blockIdx.y * 64;
    const int lr = tid >> 2;
    const int lk = (tid & 3) * 8;
    const int w    = tid >> 6;
    const int lane = tid & 63;
    const int mrow = 16 * w + (lane & 15);
    const int ksel = (lane >> 4) * 8;

    floatx4 acc0 = {0.f,0.f,0.f,0.f}, acc1 = acc0, acc2 = acc0, acc3 = acc0;

    for (int k0 = 0; k0 < K; k0 += 32) {
        short8 av = {0,0,0,0,0,0,0,0};
        if (row0 + lr < M)
            av = *(const short8*)(A + (size_t)(row0 + lr) * K + k0 + lk);
        *(short8*)&As[lr][lk] = av;
        *(short8*)&Bs[lr][lk] =
            *(const short8*)(Bt + (size_t)(col0 + lr) * K + k0 + lk);
        __syncthreads();
        short8 af = *(const short8*)&As[mrow][ksel];
        short8 b0 = *(const short8*)&Bs[ 0 + (lane & 15)][ksel];
        short8 b1 = *(const short8*)&Bs[16 + (lane & 15)][ksel];
        short8 b2 = *(const short8*)&Bs[32 + (lane & 15)][ksel];
        short8 b3 = *(const short8*)&Bs[48 + (lane & 15)][ksel];
        acc0 = __builtin_amdgcn_mfma_f32_16x16x32_bf16(af, b0, acc0, 0, 0, 0);
        acc1 = __builtin_amdgcn_mfma_f32_16x16x32_bf16(af, b1, acc1, 0, 0, 0);
        acc2 = __builtin_amdgcn_mfma_f32_16x16x32_bf16(af, b2, acc2, 0, 0, 0);
        acc3 = __builtin_amdgcn_mfma_f32_16x16x32_bf16(af, b3, acc3, 0, 0, 0);
        __syncthreads();
    }

    const int rbase = row0 + 16 * w + (lane >> 4) * 4;
    floatx4 av[4] = {acc0, acc1, acc2, acc3};
#pragma unroll
    for (int c = 0; c < 4; ++c) {
        const int col = col0 + 16 * c + (lane & 15);
        const float bv = bias ? bias[col] : 0.f;
#pragma unroll
        for (int i = 0; i < 4; ++i) {
            const int row = rbase + i;
            if (row < M) {
                float v = av[c][i] + bv;
                if (do_relu) v = fmaxf(v, 0.f);
                const size_t off = (size_t)row * 256 + col;
                if (Cf) Cf[off] = v;
                if (Cb) Cb[off] = f2bf(v);
            }
        }
    }

    // fused per-row attention dots (raw fp32 acc, pre-bias/relu)
    if (attS) {
        const int cix = lane & 15;
        float sA[4] = {0.f,0.f,0.f,0.f}, sD[4] = {0.f,0.f,0.f,0.f};
#pragma unroll
        for (int c = 0; c < 4; ++c) {
            const float as_v = attS[col0 + 16 * c + cix];
            const float ad_v = attD ? attD[col0 + 16 * c + cix] : 0.f;
#pragma unroll
            for (int i = 0; i < 4; ++i) {
                sA[i] += av[c][i] * as_v;
                sD[i] += av[c][i] * ad_v;
            }
        }
#pragma unroll
        for (int off = 1; off < 16; off <<= 1) {
#pragma unroll
            for (int i = 0; i < 4; ++i) {
                sA[i] += __shfl_xor(sA[i], off);
                sD[i] += __shfl_xor(sD[i], off);
            }
        }
        if (cix == 0) {
            const int head = col0 >> 6;
#pragma unroll
            for (int i = 0; i < 4; ++i) {
                const int row = rbase + i;
                if (row < M) {
                    aSo[(size_t)row * 4 + head] = sA[i];
                    if (aDo) aDo[(size_t)row * 4 + head] = sD[i];
                }
            }
        }
    }
}

// ------ fold ct-dst attention through the projection: wfold[k,h] ------------
__global__ void fold_ct(const float* __restrict__ W, const float* __restrict__ ad,
                        float* __restrict__ wfold)
{
    int idx = blockIdx.x * blockDim.x + threadIdx.x; // 1024 = 256*4
    if (idx >= 1024) return;
    int k = idx >> 2, h = idx & 3;
    float s = 0.f;
#pragma unroll 8
    for (int c = 0; c < 64; ++c) s += W[(size_t)k * 256 + h * 64 + c] * ad[h * 64 + c];
    wfold[idx] = s;
}

// aD[n,h] = ht[n,:] @ wfold[:,h]   (ht in bf16)
__global__ __launch_bounds__(256) void alpha_from_fold(
    const ushort* __restrict__ ht, const float* __restrict__ wfold,
    float* __restrict__ aD, int N)
{
    __shared__ float wf[1024];
    const int tid = threadIdx.x;
    *(float4*)&wf[tid * 4] = *(const float4*)&wfold[tid * 4];
    __syncthreads();
    const int idx = blockIdx.x * 256 + tid;
    if (idx >= N * 4) return;
    const int n = idx >> 2, h = idx & 3;
    const ushort* row = ht + (size_t)n * 256;
    float s = 0.f;
#pragma unroll
    for (int k = 0; k < 256; k += 4) {
        ushort4 r4 = *(const ushort4*)(row + k);
        s += bf2f(r4.x) * wf[(k + 0) * 4 + h] + bf2f(r4.y) * wf[(k + 1) * 4 + h]
           + bf2f(r4.z) * wf[(k + 2) * 4 + h] + bf2f(r4.w) * wf[(k + 3) * 4 + h];
    }
    aD[idx] = s;
}

// ---- topology-only bucket build, XCD-range-partitioned ---------------------
// range = blockIdx.x & 7 (== XCD under round-robin dispatch). Each range
// group streams ALL edges, materializes only keys in [lo,hi). Bucket slice
// per range ~NT/8*CAP*8B fits one XCD L2 -> lines fill before writeback.
// tt: bktA keyed by dst (s2d gather), bktB keyed by src (d2s gather).
__global__ __launch_bounds__(256) void build_buckets_tt_ranged(
    const int* __restrict__ src, const int* __restrict__ dst, int E, int RS,
    int* __restrict__ cntA, int2* __restrict__ bktA,
    int* __restrict__ cntB, int2* __restrict__ bktB)
{
    const int range = blockIdx.x & (NRANGE - 1);
    const int lo = range * RS, hi = lo + RS;
    const int nb = gridDim.x >> 3;            // blocks per range
    const int j  = blockIdx.x >> 3;
    const int stride = nb * blockDim.x;
    for (int e = j * blockDim.x + threadIdx.x; e < E; e += stride) {
        const int s = src[e], d = dst[e];
        if (d >= lo && d < hi) {
            const int pa = atomicAdd(&cntA[d], 1);
            if (pa < CAP) bktA[(size_t)d * CAP + pa] = make_int2(s, e);
        }
        if (s >= lo && s < hi) {
            const int pb = atomicAdd(&cntB[s], 1);
            if (pb < CAP) bktB[(size_t)s * CAP + pb] = make_int2(d, e);
        }
    }
}

__global__ __launch_bounds__(256) void build_bucket_ranged(
    const int* __restrict__ src, const int* __restrict__ dst, int E, int RS,
    int* __restrict__ cnt, int2* __restrict__ bkt)
{
    const int range = blockIdx.x & (NRANGE - 1);
    const int lo = range * RS, hi = lo + RS;
    const int nb = gridDim.x >> 3;
    const int j  = blockIdx.x >> 3;
    const int stride = nb * blockDim.x;
    for (int e = j * blockDim.x + threadIdx.x; e < E; e += stride) {
        const int s = src[e], d = dst[e];
        if (d >= lo && d < hi) {
            const int p = atomicAdd(&cnt[d], 1);
            if (p < CAP) bkt[(size_t)d * CAP + p] = make_int2(s, e);
        }
    }
}

// ---- per-edge softmax numerators (no max shift, zero atomics) --------------
__global__ __launch_bounds__(256) void edge_w(
    const int* __restrict__ src, const int* __restrict__ dst, int E,
    const float* __restrict__ aS, const float* __restrict__ aD,
    float* __restrict__ w_e)
{
    const int e = blockIdx.x * blockDim.x + threadIdx.x;
    if (e >= E) return;
    const int s = src[e], d = dst[e];
    const float4 s4 = ((const float4*)aS)[s];
    const float4 d4 = ((const float4*)aD)[d];
    float4 a;
    a.x = s4.x + d4.x; a.x = (a.x >= 0.f) ? a.x : LRELU_SLOPE * a.x;
    a.y = s4.y + d4.y; a.y = (a.y >= 0.f) ? a.y : LRELU_SLOPE * a.y;
    a.z = s4.z + d4.z; a.z = (a.z >= 0.f) ? a.z : LRELU_SLOPE * a.z;
    a.w = s4.w + d4.w; a.w = (a.w >= 0.f) ? a.w : LRELU_SLOPE * a.w;
    float4 w;
    w.x = __expf(a.x); w.y = __expf(a.y);
    w.z = __expf(a.z); w.w = __expf(a.w);
    ((float4*)w_e)[e] = w;
}

// ---- gather: one WAVE per node, 64 lanes x ushort4 = 256 channels ----------
// den accumulated in-loop (w already in registers). Unrolled x4 for MLP.
__global__ __launch_bounds__(256) void gat_gather_w(
    const int* __restrict__ cnt, const int2* __restrict__ bucket,
    const float* __restrict__ w_e, const float* __restrict__ aS,
    const float* __restrict__ aD, const ushort* __restrict__ xs,
    const float* __restrict__ bias, float scale, float* __restrict__ acc,
    int N, int has_self, int init)
{
    const int n = blockIdx.x * 4 + (threadIdx.x >> 6);
    if (n >= N) return;
    const int lane = threadIdx.x & 63;
    const int h  = lane >> 4;          // 16 lanes per head
    const int c4 = lane << 2;          // channel base, 0..252

    float4 facc = {0.f, 0.f, 0.f, 0.f};
    float dacc = 0.f;
    if (has_self) {
        float a = aS[(size_t)n * 4 + h] + aD[(size_t)n * 4 + h];
        a = (a >= 0.f) ? a : LRELU_SLOPE * a;
        const float w = __expf(a);
        const ushort4 x = *(const ushort4*)(xs + (size_t)n * 256 + c4);
        facc.x = w * bf2f(x.x); facc.y = w * bf2f(x.y);
        facc.z = w * bf2f(x.z); facc.w = w * bf2f(x.w);
        dacc = w;
    }

    const int deg = min(cnt[n], CAP);
    const int2* b = bucket + (size_t)n * CAP;
    int i = 0;
    for (; i + 4 <= deg; i += 4) {
        const int2 e0 = b[i], e1 = b[i + 1], e2 = b[i + 2], e3 = b[i + 3];
        const float w0 = w_e[(size_t)e0.y * 4 + h];
        const float w1 = w_e[(size_t)e1.y * 4 + h];
        const float w2 = w_e[(size_t)e2.y * 4 + h];
        const float w3 = w_e[(size_t)e3.y * 4 + h];
        const ushort4 x0 = *(const ushort4*)(xs + (size_t)e0.x * 256 + c4);
        const ushort4 x1 = *(const ushort4*)(xs + (size_t)e1.x * 256 + c4);
        const ushort4 x2 = *(const ushort4*)(xs + (size_t)e2.x * 256 + c4);
        const ushort4 x3 = *(const ushort4*)(xs + (size_t)e3.x * 256 + c4);
        facc.x += w0 * bf2f(x0.x) + w1 * bf2f(x1.x) + w2 * bf2f(x2.x) + w3 * bf2f(x3.x);
        facc.y += w0 * bf2f(x0.y) + w1 * bf2f(x1.y) + w2 * bf2f(x2.y) + w3 * bf2f(x3.y);
        facc.z += w0 * bf2f(x0.z) + w1 * bf2f(x1.z) + w2 * bf2f(x2.z) + w3 * bf2f(x3.z);
        facc.w += w0 * bf2f(x0.w) + w1 * bf2f(x1.w) + w2 * bf2f(x2.w) + w3 * bf2f(x3.w);
        dacc   += w0 + w1 + w2 + w3;
    }
    for (; i < deg; ++i) {
        const int2 e = b[i];
        const float w = w_e[(size_t)e.y * 4 + h];
        const ushort4 x = *(const ushort4*)(xs + (size_t)e.x * 256 + c4);
        facc.x += w * bf2f(x.x); facc.y += w * bf2f(x.y);
        facc.z += w * bf2f(x.z); facc.w += w * bf2f(x.w);
        dacc   += w;
    }

    const float inv = 1.f / fmaxf(dacc, 1e-16f);
    const float4 bv = *(const float4*)(bias + c4);
    float4 v;
    v.x = scale * (facc.x * inv + bv.x);
    v.y = scale * (facc.y * inv + bv.y);
    v.z = scale * (facc.z * inv + bv.z);
    v.w = scale * (facc.w * inv + bv.w);
    float4* ap = (float4*)(acc + (size_t)n * 256 + c4);
    if (init) {
        *ap = v;
    } else {
        float4 o = *ap;
        o.x += v.x; o.y += v.y; o.z += v.z; o.w += v.w;
        *ap = o;
    }
}

// ---- skip + relu + cast: htb = bf16(relu(acc + htb)) in place --------------
__global__ __launch_bounds__(256) void combine_relu(
    const float* __restrict__ acc, ushort* __restrict__ htb, int total4)
{
    const int idx = blockIdx.x * blockDim.x + threadIdx.x;
    if (idx >= total4) return;
    float4 a = ((const float4*)acc)[idx];
    ushort4 hb = ((const ushort4*)htb)[idx];
    ushort4 o;
    o.x = f2bf(fmaxf(a.x + bf2f(hb.x), 0.f));
    o.y = f2bf(fmaxf(a.y + bf2f(hb.y), 0.f));
    o.z = f2bf(fmaxf(a.z + bf2f(hb.z), 0.f));
    o.w = f2bf(fmaxf(a.w + bf2f(hb.w), 0.f));
    ((ushort4*)htb)[idx] = o;
}

// ---------------------------------------------------------------------------
extern "C" void kernel_launch(void* const* d_in, const int* in_sizes, int n_in,
                              void* d_out, int out_size, void* d_ws, size_t ws_size,
                              hipStream_t stream)
{
    const int NT   = in_sizes[0] / 128;
    const int NC   = in_sizes[1] / 64;
    const int E_TT = in_sizes[2] / 2;
    const int E_CT = in_sizes[3];

    const float* x_target = (const float*)d_in[0];
    const float* x_context= (const float*)d_in[1];
    const int*   ei_tt    = (const int*)d_in[2];
    const int*   ei_ct_src= (const int*)d_in[3];
    const int*   ei_ct_dst= (const int*)d_in[4];
    const float* Wt   = (const float*)d_in[5];
    const float* bt   = (const float*)d_in[6];
    const float* Wc   = (const float*)d_in[7];
    const float* bc   = (const float*)d_in[8];
    const float* W_s2d  = (const float*)d_in[9];
    const float* as_s2d = (const float*)d_in[10];
    const float* ad_s2d = (const float*)d_in[11];
    const float* b_s2d  = (const float*)d_in[12];
    const float* W_d2s  = (const float*)d_in[13];
    const float* as_d2s = (const float*)d_in[14];
    const float* ad_d2s = (const float*)d_in[15];
    const float* b_d2s  = (const float*)d_in[16];
    const float* W_ct_src = (const float*)d_in[17];
    const float* W_ct_dst = (const float*)d_in[18];
    const float* as_ct  = (const float*)d_in[19];
    const float* ad_ct  = (const float*)d_in[20];
    const float* b_ct   = (const float*)d_in[21];
    const float* W_out  = (const float*)d_in[22];
    const float* b_out  = (const float*)d_in[23];
    float* out = (float*)d_out;

    const int* tt_src = ei_tt;
    const int* tt_dst = ei_tt + E_TT;

    // ---- workspace carve-up ----
    float* ws = (float*)d_ws;
    size_t o = 0;
    float* acc = ws + o;               o += (size_t)NT * 256;
    ushort* htb = (ushort*)(ws + o);   o += (size_t)NT * 128;   // NT*256 bf16
    ushort* Pb  = (ushort*)(ws + o);   o += (size_t)NT * 128;
    ushort* hcb = (ushort*)(ws + o);   o += (size_t)NC * 128;
    ushort* PSb = (ushort*)(ws + o);   o += (size_t)NC * 128;
    ushort* xtb = (ushort*)(ws + o);   o += (size_t)NT * 64;    // NT*128 bf16
    ushort* xcb = (ushort*)(ws + o);   o += (size_t)NC * 32;
    float* w_e = ws + o;               o += (size_t)E_TT * 4;
    int2* bktA = (int2*)(ws + o);      o += (size_t)NT * CAP * 2;
    int2* bktB = (int2*)(ws + o);      o += (size_t)NT * CAP * 2;
    int2* bktC = (int2*)(ws + o);      o += (size_t)NT * CAP * 2;
    float* aS  = ws + o;               o += (size_t)NT * 4;
    float* aD  = ws + o;               o += (size_t)NT * 4;
    int*   cntA = (int*)(ws + o);      o += (size_t)NT;
    int*   cntB = (int*)(ws + o);      o += (size_t)NT;
    int*   cntC = (int*)(ws + o);      o += (size_t)NT;
    float* wfold = ws + o;             o += 1024;
    ushort* WtT   = (ushort*)(ws + o); o += 128 * 256 / 2;
    ushort* WcT   = (ushort*)(ws + o); o += 64 * 256 / 2;
    ushort* Ws2dT = (ushort*)(ws + o); o += 256 * 256 / 2;
    ushort* Wd2sT = (ushort*)(ws + o); o += 256 * 256 / 2;
    ushort* WctsT = (ushort*)(ws + o); o += 256 * 256 / 2;
    ushort* WoutT = (ushort*)(ws + o); o += 256 * 256 / 2;
    (void)ws_size; (void)n_in; (void)out_size;

    const dim3 blk(256);
    const int gN4 = (NT * 4 + 255) / 256;
    const int gGat = (NT + 3) / 4;
    const int RS = (NT + NRANGE - 1) / NRANGE;   // node-range size per XCD

    auto gemm = [&](const ushort* A, const ushort* Bt, const float* bias,
                    float* Cf, ushort* Cb, int M, int K, int relu,
                    const float* attS, const float* attD, float* aSo, float* aDo) {
        dim3 grid((M + 63) / 64, 4);
        hipLaunchKernelGGL(gemm_bf16, grid, blk, 0, stream, A, Bt, bias, Cf, Cb,
                           M, K, relu, attS, attD, aSo, aDo);
    };

    // 0) casts, weight transposes, topology buckets (feature-independent)
    hipMemsetAsync(cntA, 0, (size_t)NT * 3 * sizeof(int), stream); // A,B,C contiguous
    hipLaunchKernelGGL(cast_bf16, dim3((NT * 128 / 4 + 255) / 256), blk, 0, stream,
                       x_target, xtb, NT * 128 / 4);
    hipLaunchKernelGGL(cast_bf16, dim3((NC * 64 / 4 + 255) / 256), blk, 0, stream,
                       x_context, xcb, NC * 64 / 4);
    hipLaunchKernelGGL(wtrans, dim3(128), blk, 0, stream, Wt, WtT, 128);
    hipLaunchKernelGGL(wtrans, dim3(64),  blk, 0, stream, Wc, WcT, 64);
    hipLaunchKernelGGL(wtrans, dim3(256), blk, 0, stream, W_s2d, Ws2dT, 256);
    hipLaunchKernelGGL(wtrans, dim3(256), blk, 0, stream, W_d2s, Wd2sT, 256);
    hipLaunchKernelGGL(wtrans, dim3(256), blk, 0, stream, W_ct_src, WctsT, 256);
    hipLaunchKernelGGL(wtrans, dim3(256), blk, 0, stream, W_out, WoutT, 256);
    // 64 blocks/range * 8 ranges: each range group streams all E edges,
    // writes only its own 1/8 bucket slice (fits one XCD L2).
    hipLaunchKernelGGL(build_buckets_tt_ranged, dim3(64 * NRANGE), blk, 0, stream,
                       tt_src, tt_dst, E_TT, RS, cntA, bktA, cntB, bktB);
    hipLaunchKernelGGL(build_bucket_ranged, dim3(64 * NRANGE), blk, 0, stream,
                       ei_ct_src, ei_ct_dst, E_CT, RS, cntC, bktC);

    // 1) pretransform
    gemm(xtb, WtT, bt, nullptr, htb, NT, 128, 1, nullptr, nullptr, nullptr, nullptr);
    gemm(xcb, WcT, bc, nullptr, hcb, NC, 64, 1, nullptr, nullptr, nullptr, nullptr);

    // ---- GAT s2d ----
    gemm(htb, Ws2dT, nullptr, nullptr, Pb, NT, 256, 0, as_s2d, ad_s2d, aS, aD);
    hipLaunchKernelGGL(edge_w, dim3((E_TT + 255) / 256), blk, 0, stream,
                       tt_src, tt_dst, E_TT, aS, aD, w_e);
    hipLaunchKernelGGL(gat_gather_w, dim3(gGat), blk, 0, stream,
                       cntA, bktA, w_e, aS, aD, Pb, b_s2d, 0.25f, acc, NT, 1, 1);

    // ---- GAT d2s (reversed: msg src = tt_dst[e], msg dst = tt_src[e]) ----
    gemm(htb, Wd2sT, nullptr, nullptr, Pb, NT, 256, 0, as_d2s, ad_d2s, aS, aD);
    hipLaunchKernelGGL(edge_w, dim3((E_TT + 255) / 256), blk, 0, stream,
                       tt_dst, tt_src, E_TT, aS, aD, w_e);
    hipLaunchKernelGGL(gat_gather_w, dim3(gGat), blk, 0, stream,
                       cntB, bktB, w_e, aS, aD, Pb, b_d2s, 0.25f, acc, NT, 1, 0);

    // ---- GAT ct (no self loops; aD via folded projection) ----
    gemm(hcb, WctsT, nullptr, nullptr, PSb, NC, 256, 0, as_ct, nullptr, aS, nullptr);
    hipLaunchKernelGGL(fold_ct, dim3(4), blk, 0, stream, W_ct_dst, ad_ct, wfold);
    hipLaunchKernelGGL(alpha_from_fold, dim3(gN4), blk, 0, stream, htb, wfold, aD, NT);
    hipLaunchKernelGGL(edge_w, dim3((E_CT + 255) / 256), blk, 0, stream,
                       ei_ct_src, ei_ct_dst, E_CT, aS, aD, w_e);
    hipLaunchKernelGGL(gat_gather_w, dim3(gGat), blk, 0, stream,
                       cntC, bktC, w_e, aS, aD, PSb, b_ct, 0.5f, acc, NT, 0, 0);

    // ---- skip + relu (bf16 in place), final linear ----
    hipLaunchKernelGGL(combine_relu, dim3((NT * 64 + 255) / 256), blk, 0, stream,
                       acc, htb, NT * 64);
    gemm(htb, WoutT, b_out, out, nullptr, NT, 256, 0, nullptr, nullptr, nullptr, nullptr);
}

// Round 2
// 451.170 us; speedup vs baseline: 1.1580x; 1.1580x over previous
//
#include <hip/hip_runtime.h>
#include <hip/hip_bf16.h>
#include <cstdint>
#include <cstddef>

// ---------------------------------------------------------------------------
// STGNN forward. Round 7: single fused gather.
//  - R6 post-mortem: ranged bucket build was neutral; profile now shows the
//    3 gat_gather_w dispatches (3x54us, 210MB each) as the cost center. The
//    fp32 acc scratch round-trips ~300MB and w_e another ~90MB -- schedule
//    artifacts, not algorithm.
//  - Now: ONE gat_gather_fused does s2d + d2s + ct gathers per node with the
//    combination held in registers, computes edge weights in-kernel from
//    aS[partner]+aD[n] (edge_w kernels + w_e buffer deleted), and writes
//    htb = bf16(relu(sum + ht)) directly (acc buffer + combine_relu deleted).
//  - Buckets store partner-node only (int, not int2): edge-id was only needed
//    to index w_e. Halves bucket build writes and bucket fetch.
//  - s2d / d2s project into separate buffers Pb1/Pb2 so all GEMMs precede the
//    single gather.
// ---------------------------------------------------------------------------

#define LRELU_SLOPE 0.2f
#define CAP 64
#define NRANGE 8

typedef __attribute__((ext_vector_type(8))) short short8;
typedef __attribute__((ext_vector_type(4))) float floatx4;

__device__ __forceinline__ float bf2f(ushort u) {
    union { unsigned int u32; float f; } v; v.u32 = ((unsigned int)u) << 16; return v.f;
}
__device__ __forceinline__ ushort f2bf(float x) {
    union { float f; unsigned int u; } v; v.f = x;
    unsigned int r = (v.u + 0x7FFFu + ((v.u >> 16) & 1u)) >> 16;
    return (ushort)r;
}

// ---------------- elementwise fp32 -> bf16 cast (4/thread) ------------------
__global__ __launch_bounds__(256) void cast_bf16(
    const float* __restrict__ x, ushort* __restrict__ y, int n4)
{
    const int idx = blockIdx.x * blockDim.x + threadIdx.x;
    if (idx >= n4) return;
    float4 v = ((const float4*)x)[idx];
    ushort4 o;
    o.x = f2bf(v.x); o.y = f2bf(v.y); o.z = f2bf(v.z); o.w = f2bf(v.w);
    ((ushort4*)y)[idx] = o;
}

// ------------- weight transpose+cast: W[K][256] f32 -> WT[256][K] bf16 ------
__global__ __launch_bounds__(256) void wtrans(
    const float* __restrict__ W, ushort* __restrict__ WT, int K)
{
    const int idx = blockIdx.x * blockDim.x + threadIdx.x;
    if (idx >= K * 256) return;
    const int k = idx >> 8, n = idx & 255;
    WT[n * K + k] = f2bf(W[idx]);
}

// ---------------- bf16 MFMA GEMM: C[M,256] = act(A[M,K] @ B + bias) ---------
// blockIdx.y = head (64 cols). Optional fused per-row attention dot:
// aSo[row,head] = <C_row_head, attS_head>, same for aDo.
__global__ __launch_bounds__(256) void gemm_bf16(
    const ushort* __restrict__ A, const ushort* __restrict__ Bt,
    const float* __restrict__ bias, float* __restrict__ Cf,
    ushort* __restrict__ Cb, int M, int K, int do_relu,
    const float* __restrict__ attS, const float* __restrict__ attD,
    float* __restrict__ aSo, float* __restrict__ aDo)
{
    __shared__ short As[64][40];   // +8 pad
    __shared__ short Bs[64][40];
    const int tid  = threadIdx.x;
    const int row0 = blockIdx.x * 64;
    const int col0 = blockIdx.y * 64;
    const int lr = tid >> 2;
    const int lk = (tid & 3) * 8;
    const int w    = tid >> 6;
    const int lane = tid & 63;
    const int mrow = 16 * w + (lane & 15);
    const int ksel = (lane >> 4) * 8;

    floatx4 acc0 = {0.f,0.f,0.f,0.f}, acc1 = acc0, acc2 = acc0, acc3 = acc0;

    for (int k0 = 0; k0 < K; k0 += 32) {
        short8 av = {0,0,0,0,0,0,0,0};
        if (row0 + lr < M)
            av = *(const short8*)(A + (size_t)(row0 + lr) * K + k0 + lk);
        *(short8*)&As[lr][lk] = av;
        *(short8*)&Bs[lr][lk] =
            *(const short8*)(Bt + (size_t)(col0 + lr) * K + k0 + lk);
        __syncthreads();
        short8 af = *(const short8*)&As[mrow][ksel];
        short8 b0 = *(const short8*)&Bs[ 0 + (lane & 15)][ksel];
        short8 b1 = *(const short8*)&Bs[16 + (lane & 15)][ksel];
        short8 b2 = *(const short8*)&Bs[32 + (lane & 15)][ksel];
        short8 b3 = *(const short8*)&Bs[48 + (lane & 15)][ksel];
        acc0 = __builtin_amdgcn_mfma_f32_16x16x32_bf16(af, b0, acc0, 0, 0, 0);
        acc1 = __builtin_amdgcn_mfma_f32_16x16x32_bf16(af, b1, acc1, 0, 0, 0);
        acc2 = __builtin_amdgcn_mfma_f32_16x16x32_bf16(af, b2, acc2, 0, 0, 0);
        acc3 = __builtin_amdgcn_mfma_f32_16x16x32_bf16(af, b3, acc3, 0, 0, 0);
        __syncthreads();
    }

    const int rbase = row0 + 16 * w + (lane >> 4) * 4;
    floatx4 av[4] = {acc0, acc1, acc2, acc3};
#pragma unroll
    for (int c = 0; c < 4; ++c) {
        const int col = col0 + 16 * c + (lane & 15);
        const float bv = bias ? bias[col] : 0.f;
#pragma unroll
        for (int i = 0; i < 4; ++i) {
            const int row = rbase + i;
            if (row < M) {
                float v = av[c][i] + bv;
                if (do_relu) v = fmaxf(v, 0.f);
                const size_t off = (size_t)row * 256 + col;
                if (Cf) Cf[off] = v;
                if (Cb) Cb[off] = f2bf(v);
            }
        }
    }

    // fused per-row attention dots (raw fp32 acc, pre-bias/relu)
    if (attS) {
        const int cix = lane & 15;
        float sA[4] = {0.f,0.f,0.f,0.f}, sD[4] = {0.f,0.f,0.f,0.f};
#pragma unroll
        for (int c = 0; c < 4; ++c) {
            const float as_v = attS[col0 + 16 * c + cix];
            const float ad_v = attD ? attD[col0 + 16 * c + cix] : 0.f;
#pragma unroll
            for (int i = 0; i < 4; ++i) {
                sA[i] += av[c][i] * as_v;
                sD[i] += av[c][i] * ad_v;
            }
        }
#pragma unroll
        for (int off = 1; off < 16; off <<= 1) {
#pragma unroll
            for (int i = 0; i < 4; ++i) {
                sA[i] += __shfl_xor(sA[i], off);
                sD[i] += __shfl_xor(sD[i], off);
            }
        }
        if (cix == 0) {
            const int head = col0 >> 6;
#pragma unroll
            for (int i = 0; i < 4; ++i) {
                const int row = rbase + i;
                if (row < M) {
                    aSo[(size_t)row * 4 + head] = sA[i];
                    if (aDo) aDo[(size_t)row * 4 + head] = sD[i];
                }
            }
        }
    }
}

// ------ fold ct-dst attention through the projection: wfold[k,h] ------------
__global__ void fold_ct(const float* __restrict__ W, const float* __restrict__ ad,
                        float* __restrict__ wfold)
{
    int idx = blockIdx.x * blockDim.x + threadIdx.x; // 1024 = 256*4
    if (idx >= 1024) return;
    int k = idx >> 2, h = idx & 3;
    float s = 0.f;
#pragma unroll 8
    for (int c = 0; c < 64; ++c) s += W[(size_t)k * 256 + h * 64 + c] * ad[h * 64 + c];
    wfold[idx] = s;
}

// aD[n,h] = ht[n,:] @ wfold[:,h]   (ht in bf16)
__global__ __launch_bounds__(256) void alpha_from_fold(
    const ushort* __restrict__ ht, const float* __restrict__ wfold,
    float* __restrict__ aD, int N)
{
    __shared__ float wf[1024];
    const int tid = threadIdx.x;
    *(float4*)&wf[tid * 4] = *(const float4*)&wfold[tid * 4];
    __syncthreads();
    const int idx = blockIdx.x * 256 + tid;
    if (idx >= N * 4) return;
    const int n = idx >> 2, h = idx & 3;
    const ushort* row = ht + (size_t)n * 256;
    float s = 0.f;
#pragma unroll
    for (int k = 0; k < 256; k += 4) {
        ushort4 r4 = *(const ushort4*)(row + k);
        s += bf2f(r4.x) * wf[(k + 0) * 4 + h] + bf2f(r4.y) * wf[(k + 1) * 4 + h]
           + bf2f(r4.z) * wf[(k + 2) * 4 + h] + bf2f(r4.w) * wf[(k + 3) * 4 + h];
    }
    aD[idx] = s;
}

// ---- topology-only bucket build, XCD-range-partitioned, int payload --------
// Bucket stores PARTNER NODE only (edge-id no longer needed: weights are
// computed in the gather from aS[partner]+aD[n]).
__global__ __launch_bounds__(256) void build_buckets_tt_ranged(
    const int* __restrict__ src, const int* __restrict__ dst, int E, int RS,
    int* __restrict__ cntA, int* __restrict__ bktA,
    int* __restrict__ cntB, int* __restrict__ bktB)
{
    const int range = blockIdx.x & (NRANGE - 1);
    const int lo = range * RS, hi = lo + RS;
    const int nb = gridDim.x >> 3;            // blocks per range
    const int j  = blockIdx.x >> 3;
    const int stride = nb * blockDim.x;
    for (int e = j * blockDim.x + threadIdx.x; e < E; e += stride) {
        const int s = src[e], d = dst[e];
        if (d >= lo && d < hi) {
            const int pa = atomicAdd(&cntA[d], 1);
            if (pa < CAP) bktA[(size_t)d * CAP + pa] = s;
        }
        if (s >= lo && s < hi) {
            const int pb = atomicAdd(&cntB[s], 1);
            if (pb < CAP) bktB[(size_t)s * CAP + pb] = d;
        }
    }
}

__global__ __launch_bounds__(256) void build_bucket_ranged(
    const int* __restrict__ src, const int* __restrict__ dst, int E, int RS,
    int* __restrict__ cnt, int* __restrict__ bkt)
{
    const int range = blockIdx.x & (NRANGE - 1);
    const int lo = range * RS, hi = lo + RS;
    const int nb = gridDim.x >> 3;
    const int j  = blockIdx.x >> 3;
    const int stride = nb * blockDim.x;
    for (int e = j * blockDim.x + threadIdx.x; e < E; e += stride) {
        const int s = src[e], d = dst[e];
        if (d >= lo && d < hi) {
            const int p = atomicAdd(&cnt[d], 1);
            if (p < CAP) bkt[(size_t)d * CAP + p] = s;
        }
    }
}

// ---- one GAT accumulation phase (inlined 3x in the fused gather) -----------
__device__ __forceinline__ void gat_phase(
    int n, int h, int c4,
    const int* __restrict__ cnt, const int* __restrict__ bkt,
    const float* __restrict__ aS, const float* __restrict__ aD,
    const ushort* __restrict__ X, const float* __restrict__ bias,
    float scale, int has_self, float4& out)
{
    const float aDn = aD[(size_t)n * 4 + h];
    float4 f = {0.f, 0.f, 0.f, 0.f};
    float den = 0.f;
    if (has_self) {
        float a = aS[(size_t)n * 4 + h] + aDn;
        a = (a >= 0.f) ? a : LRELU_SLOPE * a;
        const float w = __expf(a);
        const ushort4 x = *(const ushort4*)(X + (size_t)n * 256 + c4);
        f.x = w * bf2f(x.x); f.y = w * bf2f(x.y);
        f.z = w * bf2f(x.z); f.w = w * bf2f(x.w);
        den = w;
    }
    const int deg = min(cnt[n], CAP);
    const int* b = bkt + (size_t)n * CAP;
    int i = 0;
    for (; i + 4 <= deg; i += 4) {
        const int s0 = b[i], s1 = b[i + 1], s2 = b[i + 2], s3 = b[i + 3];
        float a0 = aS[(size_t)s0 * 4 + h] + aDn;
        float a1 = aS[(size_t)s1 * 4 + h] + aDn;
        float a2 = aS[(size_t)s2 * 4 + h] + aDn;
        float a3 = aS[(size_t)s3 * 4 + h] + aDn;
        a0 = (a0 >= 0.f) ? a0 : LRELU_SLOPE * a0;
        a1 = (a1 >= 0.f) ? a1 : LRELU_SLOPE * a1;
        a2 = (a2 >= 0.f) ? a2 : LRELU_SLOPE * a2;
        a3 = (a3 >= 0.f) ? a3 : LRELU_SLOPE * a3;
        const float w0 = __expf(a0), w1 = __expf(a1);
        const float w2 = __expf(a2), w3 = __expf(a3);
        const ushort4 x0 = *(const ushort4*)(X + (size_t)s0 * 256 + c4);
        const ushort4 x1 = *(const ushort4*)(X + (size_t)s1 * 256 + c4);
        const ushort4 x2 = *(const ushort4*)(X + (size_t)s2 * 256 + c4);
        const ushort4 x3 = *(const ushort4*)(X + (size_t)s3 * 256 + c4);
        f.x += w0 * bf2f(x0.x) + w1 * bf2f(x1.x) + w2 * bf2f(x2.x) + w3 * bf2f(x3.x);
        f.y += w0 * bf2f(x0.y) + w1 * bf2f(x1.y) + w2 * bf2f(x2.y) + w3 * bf2f(x3.y);
        f.z += w0 * bf2f(x0.z) + w1 * bf2f(x1.z) + w2 * bf2f(x2.z) + w3 * bf2f(x3.z);
        f.w += w0 * bf2f(x0.w) + w1 * bf2f(x1.w) + w2 * bf2f(x2.w) + w3 * bf2f(x3.w);
        den += w0 + w1 + w2 + w3;
    }
    for (; i < deg; ++i) {
        const int s = b[i];
        float a = aS[(size_t)s * 4 + h] + aDn;
        a = (a >= 0.f) ? a : LRELU_SLOPE * a;
        const float w = __expf(a);
        const ushort4 x = *(const ushort4*)(X + (size_t)s * 256 + c4);
        f.x += w * bf2f(x.x); f.y += w * bf2f(x.y);
        f.z += w * bf2f(x.z); f.w += w * bf2f(x.w);
        den += w;
    }
    const float inv = 1.f / fmaxf(den, 1e-16f);
    const float4 bv = *(const float4*)(bias + c4);
    out.x += scale * (f.x * inv + bv.x);
    out.y += scale * (f.y * inv + bv.y);
    out.z += scale * (f.z * inv + bv.z);
    out.w += scale * (f.w * inv + bv.w);
}

// ---- fused gather: all 3 GATs + skip + relu + bf16 cast, one wave/node -----
__global__ __launch_bounds__(256) void gat_gather_fused(
    const int* __restrict__ cntA, const int* __restrict__ bktA,
    const float* __restrict__ aS1, const float* __restrict__ aD1,
    const ushort* __restrict__ P1, const float* __restrict__ b1,
    const int* __restrict__ cntB, const int* __restrict__ bktB,
    const float* __restrict__ aS2, const float* __restrict__ aD2,
    const ushort* __restrict__ P2, const float* __restrict__ b2,
    const int* __restrict__ cntC, const int* __restrict__ bktC,
    const float* __restrict__ aSc, const float* __restrict__ aDc,
    const ushort* __restrict__ Pc, const float* __restrict__ b3,
    ushort* __restrict__ htb, int N)
{
    const int n = blockIdx.x * 4 + (threadIdx.x >> 6);
    if (n >= N) return;
    const int lane = threadIdx.x & 63;
    const int h  = lane >> 4;          // 16 lanes per head
    const int c4 = lane << 2;          // channel base, 0..252

    float4 out = {0.f, 0.f, 0.f, 0.f};
    gat_phase(n, h, c4, cntA, bktA, aS1, aD1, P1, b1, 0.25f, 1, out);
    gat_phase(n, h, c4, cntB, bktB, aS2, aD2, P2, b2, 0.25f, 1, out);
    gat_phase(n, h, c4, cntC, bktC, aSc, aDc, Pc, b3, 0.50f, 0, out);

    ushort* hp = htb + (size_t)n * 256 + c4;
    const ushort4 hb = *(const ushort4*)hp;
    ushort4 o;
    o.x = f2bf(fmaxf(out.x + bf2f(hb.x), 0.f));
    o.y = f2bf(fmaxf(out.y + bf2f(hb.y), 0.f));
    o.z = f2bf(fmaxf(out.z + bf2f(hb.z), 0.f));
    o.w = f2bf(fmaxf(out.w + bf2f(hb.w), 0.f));
    *(ushort4*)hp = o;
}

// ---------------------------------------------------------------------------
extern "C" void kernel_launch(void* const* d_in, const int* in_sizes, int n_in,
                              void* d_out, int out_size, void* d_ws, size_t ws_size,
                              hipStream_t stream)
{
    const int NT   = in_sizes[0] / 128;
    const int NC   = in_sizes[1] / 64;
    const int E_TT = in_sizes[2] / 2;
    const int E_CT = in_sizes[3];

    const float* x_target = (const float*)d_in[0];
    const float* x_context= (const float*)d_in[1];
    const int*   ei_tt    = (const int*)d_in[2];
    const int*   ei_ct_src= (const int*)d_in[3];
    const int*   ei_ct_dst= (const int*)d_in[4];
    const float* Wt   = (const float*)d_in[5];
    const float* bt   = (const float*)d_in[6];
    const float* Wc   = (const float*)d_in[7];
    const float* bc   = (const float*)d_in[8];
    const float* W_s2d  = (const float*)d_in[9];
    const float* as_s2d = (const float*)d_in[10];
    const float* ad_s2d = (const float*)d_in[11];
    const float* b_s2d  = (const float*)d_in[12];
    const float* W_d2s  = (const float*)d_in[13];
    const float* as_d2s = (const float*)d_in[14];
    const float* ad_d2s = (const float*)d_in[15];
    const float* b_d2s  = (const float*)d_in[16];
    const float* W_ct_src = (const float*)d_in[17];
    const float* W_ct_dst = (const float*)d_in[18];
    const float* as_ct  = (const float*)d_in[19];
    const float* ad_ct  = (const float*)d_in[20];
    const float* b_ct   = (const float*)d_in[21];
    const float* W_out  = (const float*)d_in[22];
    const float* b_out  = (const float*)d_in[23];
    float* out = (float*)d_out;

    const int* tt_src = ei_tt;
    const int* tt_dst = ei_tt + E_TT;

    // ---- workspace carve-up (units: fp32 slots) ----
    float* ws = (float*)d_ws;
    size_t o = 0;
    ushort* htb = (ushort*)(ws + o);   o += (size_t)NT * 128;   // NT*256 bf16
    ushort* Pb1 = (ushort*)(ws + o);   o += (size_t)NT * 128;
    ushort* Pb2 = (ushort*)(ws + o);   o += (size_t)NT * 128;
    ushort* hcb = (ushort*)(ws + o);   o += (size_t)NC * 128;
    ushort* PSb = (ushort*)(ws + o);   o += (size_t)NC * 128;
    ushort* xtb = (ushort*)(ws + o);   o += (size_t)NT * 64;    // NT*128 bf16
    ushort* xcb = (ushort*)(ws + o);   o += (size_t)NC * 32;
    int* bktA = (int*)(ws + o);        o += (size_t)NT * CAP;   // int payload
    int* bktB = (int*)(ws + o);        o += (size_t)NT * CAP;
    int* bktC = (int*)(ws + o);        o += (size_t)NT * CAP;
    float* aS1 = ws + o;               o += (size_t)NT * 4;
    float* aD1 = ws + o;               o += (size_t)NT * 4;
    float* aS2 = ws + o;               o += (size_t)NT * 4;
    float* aD2 = ws + o;               o += (size_t)NT * 4;
    float* aSc = ws + o;               o += (size_t)NT * 4;     // used: NC*4
    float* aDc = ws + o;               o += (size_t)NT * 4;
    int*   cntA = (int*)(ws + o);      o += (size_t)NT;
    int*   cntB = (int*)(ws + o);      o += (size_t)NT;
    int*   cntC = (int*)(ws + o);      o += (size_t)NT;
    float* wfold = ws + o;             o += 1024;
    ushort* WtT   = (ushort*)(ws + o); o += 128 * 256 / 2;
    ushort* WcT   = (ushort*)(ws + o); o += 64 * 256 / 2;
    ushort* Ws2dT = (ushort*)(ws + o); o += 256 * 256 / 2;
    ushort* Wd2sT = (ushort*)(ws + o); o += 256 * 256 / 2;
    ushort* WctsT = (ushort*)(ws + o); o += 256 * 256 / 2;
    ushort* WoutT = (ushort*)(ws + o); o += 256 * 256 / 2;
    (void)ws_size; (void)n_in; (void)out_size;

    const dim3 blk(256);
    const int gN4 = (NT * 4 + 255) / 256;
    const int gGat = (NT + 3) / 4;
    const int RS = (NT + NRANGE - 1) / NRANGE;   // node-range size per XCD

    auto gemm = [&](const ushort* A, const ushort* Bt, const float* bias,
                    float* Cf, ushort* Cb, int M, int K, int relu,
                    const float* attS, const float* attD, float* aSo, float* aDo) {
        dim3 grid((M + 63) / 64, 4);
        hipLaunchKernelGGL(gemm_bf16, grid, blk, 0, stream, A, Bt, bias, Cf, Cb,
                           M, K, relu, attS, attD, aSo, aDo);
    };

    // 0) casts, weight transposes, topology buckets (feature-independent)
    hipMemsetAsync(cntA, 0, (size_t)NT * 3 * sizeof(int), stream); // A,B,C contiguous
    hipLaunchKernelGGL(cast_bf16, dim3((NT * 128 / 4 + 255) / 256), blk, 0, stream,
                       x_target, xtb, NT * 128 / 4);
    hipLaunchKernelGGL(cast_bf16, dim3((NC * 64 / 4 + 255) / 256), blk, 0, stream,
                       x_context, xcb, NC * 64 / 4);
    hipLaunchKernelGGL(wtrans, dim3(128), blk, 0, stream, Wt, WtT, 128);
    hipLaunchKernelGGL(wtrans, dim3(64),  blk, 0, stream, Wc, WcT, 64);
    hipLaunchKernelGGL(wtrans, dim3(256), blk, 0, stream, W_s2d, Ws2dT, 256);
    hipLaunchKernelGGL(wtrans, dim3(256), blk, 0, stream, W_d2s, Wd2sT, 256);
    hipLaunchKernelGGL(wtrans, dim3(256), blk, 0, stream, W_ct_src, WctsT, 256);
    hipLaunchKernelGGL(wtrans, dim3(256), blk, 0, stream, W_out, WoutT, 256);
    hipLaunchKernelGGL(build_buckets_tt_ranged, dim3(64 * NRANGE), blk, 0, stream,
                       tt_src, tt_dst, E_TT, RS, cntA, bktA, cntB, bktB);
    hipLaunchKernelGGL(build_bucket_ranged, dim3(64 * NRANGE), blk, 0, stream,
                       ei_ct_src, ei_ct_dst, E_CT, RS, cntC, bktC);

    // 1) pretransform
    gemm(xtb, WtT, bt, nullptr, htb, NT, 128, 1, nullptr, nullptr, nullptr, nullptr);
    gemm(xcb, WcT, bc, nullptr, hcb, NC, 64, 1, nullptr, nullptr, nullptr, nullptr);

    // 2) all three GAT projections + attention alphas
    gemm(htb, Ws2dT, nullptr, nullptr, Pb1, NT, 256, 0, as_s2d, ad_s2d, aS1, aD1);
    gemm(htb, Wd2sT, nullptr, nullptr, Pb2, NT, 256, 0, as_d2s, ad_d2s, aS2, aD2);
    gemm(hcb, WctsT, nullptr, nullptr, PSb, NC, 256, 0, as_ct, nullptr, aSc, nullptr);
    hipLaunchKernelGGL(fold_ct, dim3(4), blk, 0, stream, W_ct_dst, ad_ct, wfold);
    hipLaunchKernelGGL(alpha_from_fold, dim3(gN4), blk, 0, stream, htb, wfold, aDc, NT);

    // 3) single fused gather: s2d + d2s + ct + skip + relu + bf16 cast
    hipLaunchKernelGGL(gat_gather_fused, dim3(gGat), blk, 0, stream,
                       cntA, bktA, aS1, aD1, Pb1, b_s2d,
                       cntB, bktB, aS2, aD2, Pb2, b_d2s,
                       cntC, bktC, aSc, aDc, PSb, b_ct,
                       htb, NT);

    // 4) final linear
    gemm(htb, WoutT, b_out, out, nullptr, NT, 256, 0, nullptr, nullptr, nullptr, nullptr);
}